// Round 7
// baseline (166.846 us; speedup 1.0000x reference)
//
#include <hip/hip_runtime.h>
#include <stdint.h>

// CSWin attention, MI355X/gfx950 — r16: 2x TLP (8-wave blocks, 1 m-tile/wave).
// Shapes: B=2, H=W=64, N=4, DIM=128, HEADS=4, HEAD_DIM=32, SPLIT=2.
// Grid 1024 = (window,head) x 4 row-quarters; block 512 (8 waves);
// wave = 16 q-rows (ONE m-tile). LDS: VT bf16 [32][512] swizzled, 32KB.
//
// r16 theory: r9/r11/r12/r15 all land at ~60us with every pipe <25% busy,
// r12 halved VALU cycles (no dur change), r15's 2-deep prefetch (no change),
// dispatch-0 runs at 1/20 activity for the SAME 60us -> wall time is per-wave
// stall that ILP doesn't cover. Only untested lever: TLP. This round doubles
// waves/SIMD 4->8 (32 waves/CU): 512-thread blocks, 1 m-tile per wave,
// state halved to fit 64 VGPR (launch_bounds(512,8) = 64-cap):
//  * 2-tile K chunks (16 x K-step-32), 1-deep prefetch in 4 named float4.
//  * bv swizzle XOR applied to FULL dword index (chunk base now overlaps
//    XOR bits at 2-tile granularity).
//  * diag mask via wave-uniform branch on named sa0/sa1 (rule #20 safe).
// Predicted: VGPR<=64 & WRITE ~26-35MB (else spill -> recognize+revert),
// Occupancy ~45-60%, dur 35-45us if stall is TLP-hideable; dur ~60us
// falsifies TLP -> structural floor ~58us for this op.

typedef __bf16 bf16x8 __attribute__((ext_vector_type(8)));
typedef float f32x4 __attribute__((ext_vector_type(4)));

#if __has_builtin(__builtin_amdgcn_exp2f)
#define EXP2F __builtin_amdgcn_exp2f
#else
#define EXP2F exp2f
#endif

union U4 { uint4 u; bf16x8 v; unsigned short s[8]; };

__device__ __forceinline__ float bf2f(unsigned short h){ union{unsigned u;float f;}x; x.u=((unsigned)h)<<16; return x.f; }

// f32 pair -> packed bf16 dword (lo in low half), RTNE. 1 instr.
__device__ __forceinline__ unsigned cvtpk(float lo, float hi){
  unsigned d;
  asm("v_cvt_pk_bf16_f32 %0, %1, %2" : "=v"(d) : "v"(lo), "v"(hi));
  return d;
}
__device__ __forceinline__ U4 pack8(float4 a, float4 b){
  U4 r;
  r.u.x = cvtpk(a.x, a.y); r.u.y = cvtpk(a.z, a.w);
  r.u.z = cvtpk(b.x, b.y); r.u.w = cvtpk(b.z, b.w);
  return r;
}

// permlane swap pair primitives (gfx950).
__device__ __forceinline__ void pls32(unsigned &a, unsigned &b){
#if __has_builtin(__builtin_amdgcn_permlane32_swap)
  auto r = __builtin_amdgcn_permlane32_swap(a, b, false, false);
  a = r[0]; b = r[1];
#else
  unsigned sa_ = __shfl_xor(a, 32), sb_ = __shfl_xor(b, 32);
  bool hi = ((threadIdx.x & 32) != 0);
  unsigned na = hi ? sb_ : a, nb = hi ? b : sa_;
  a = na; b = nb;
#endif
}
__device__ __forceinline__ void pls16(unsigned &a, unsigned &b){
#if __has_builtin(__builtin_amdgcn_permlane16_swap)
  auto r = __builtin_amdgcn_permlane16_swap(a, b, false, false);
  a = r[0]; b = r[1];
#else
  unsigned sa_ = __shfl_xor(a, 16), sb_ = __shfl_xor(b, 16);
  bool hi = ((threadIdx.x & 16) != 0);
  unsigned na = hi ? sb_ : a, nb = hi ? b : sa_;
  a = na; b = nb;
#endif
}

#define C_SCALE 0.25506953149031837f  // (1/sqrt(32)) * log2(e)
#define M_SHIFT 20.0f                 // fixed log2-domain softmax shift

// LDS: VT bf16 [32 ch][512 tok] swizzled (in-row dword ^ ((d&7)<<2)), 1KB/row.
#define VT_OFF 0
#define LDS_BYTES 32768

__global__ __launch_bounds__(512, 8) void cswin_attn_kernel(
    const float* __restrict__ qg,
    const float* __restrict__ kg,
    const float* __restrict__ vg,
    const float* __restrict__ cwg,
    float* __restrict__ outg)
{
  __shared__ __align__(16) unsigned char smem[LDS_BYTES];
  const int tid = threadIdx.x;
  const int lane = tid & 63;
  const int wave = tid >> 6;          // 0..7
  const int qd = lane >> 4;
  const int n  = lane & 15;

  const int swn = (n & 7) << 2;        // XOR mask on full in-row dword index

  // XCD-sibling remap: q4-siblings share bid%8 (same XCD L2).
  const int bid = blockIdx.x;
  const int bh = ((bid >> 5) << 3) | (bid & 7);   // (window,head) 0..255
  const int q4 = (bid >> 3) & 3;                  // row-quarter 0..3
  const int head = bh & 3;
  const int bw = bh >> 2;
  const int b  = bw >> 5;
  const int jj = bw & 31;

  // token l: offset = wbase + (l>>3)*32768 + ((l>>2)&1)*512 + (l&3)*128
  const size_t wbase = (size_t)b * 2097152 + (size_t)(jj * 2) * 512 + head * 32;
  const size_t lane_base = wbase + (size_t)(n >> 3) * 32768 + (size_t)((n >> 2) & 1) * 512 +
                           (size_t)(n & 3) * 128 + qd * 8;

  const int row0  = q4 * 128 + wave * 16;   // this wave's single m-tile
  const int tilea = row0 >> 4;              // 0..31
  const int cka2  = tilea >> 1;             // 2-tile chunk holding the diag
  const int ta2   = tilea & 1;              // slot within that chunk (uniform)

  // ---- stage V -> VT bf16 (first 4 waves; 2 tokens per thread) ----
  if (tid < 256){
    int l0 = tid * 2;
    size_t off = wbase + (size_t)(l0 >> 3) * 32768 + (size_t)((l0 >> 2) & 1) * 512 + (l0 & 3) * 128;
    const float* p0 = vg + off;
    float v0[32], v1[32];
#pragma unroll
    for (int c = 0; c < 8; c++){
      float4 a = ((const float4*)p0)[c];
      v0[c*4+0]=a.x; v0[c*4+1]=a.y; v0[c*4+2]=a.z; v0[c*4+3]=a.w;
    }
#pragma unroll
    for (int c = 0; c < 8; c++){
      float4 a = ((const float4*)(p0 + 128))[c];
      v1[c*4+0]=a.x; v1[c*4+1]=a.y; v1[c*4+2]=a.z; v1[c*4+3]=a.w;
    }
#pragma unroll
    for (int d = 0; d < 32; d++)
      *(unsigned*)(smem + VT_OFF + d * 1024 + ((tid ^ ((d & 7) << 2)) << 2)) =
          cvtpk(v0[d], v1[d]);
  }

  // ---- issue Q + K chunk0 loads before the sync ----
  float4 qr0, qr1;
  {
    const float* qa = qg + lane_base + (size_t)tilea * 65536;
    qr0 = ((const float4*)qa)[0]; qr1 = ((const float4*)qa)[1];
  }
  float4 n0, n1, n2, n3;   // 1-deep K prefetch, tiles (2*ck2, 2*ck2+1)
  {
    const float* kp0 = kg + lane_base;
    const float* kp1 = kg + lane_base + 65536;
    n0 = ((const float4*)kp0)[0]; n1 = ((const float4*)kp0)[1];
    n2 = ((const float4*)kp1)[0]; n3 = ((const float4*)kp1)[1];
  }

  __syncthreads();

  U4 bq = pack8(qr0, qr1);

  f32x4 o0={0,0,0,0}, o1={0,0,0,0};
  float la = 0.f;

#pragma unroll 1
  for (int ck2 = 0; ck2 < 16; ck2++){
    U4 ak0 = pack8(n0, n1);
    U4 ak1 = pack8(n2, n3);
    if (ck2 < 15){
      const float* kp0 = kg + lane_base + (size_t)(2 * ck2 + 2) * 65536;
      const float* kp1 = kg + lane_base + (size_t)(2 * ck2 + 3) * 65536;
      n0 = ((const float4*)kp0)[0]; n1 = ((const float4*)kp0)[1];
      n2 = ((const float4*)kp1)[0]; n3 = ((const float4*)kp1)[1];
    }

    const f32x4 zero = {0.f,0.f,0.f,0.f};
    f32x4 sa0 = __builtin_amdgcn_mfma_f32_16x16x32_bf16(ak0.v, bq.v, zero, 0, 0, 0);
    f32x4 sa1 = __builtin_amdgcn_mfma_f32_16x16x32_bf16(ak1.v, bq.v, zero, 0, 0, 0);

    if (ck2 == cka2){                       // diagonal chunk (wave-uniform)
      bool dq = (qd == (n >> 2));
      if (ta2 == 0){
#pragma unroll
        for (int r = 0; r < 4; r++) if (dq && r != (n & 3)) sa0[r] = -1e30f;
      } else {
#pragma unroll
        for (int r = 0; r < 4; r++) if (dq && r != (n & 3)) sa1[r] = -1e30f;
      }
    }

    // ---- issue V-fragment reads early (hide under softmax VALU) ----
    const int idx = ck2 * 16 + 4 * qd;          // full in-row dword index
    const int xb = ((idx ^ swn) << 2);
    const unsigned char* vr0 = smem + VT_OFF + n * 1024 + xb;
    const unsigned char* vr1 = vr0 + 16 * 1024;
    U4 bv0, bv1;
    bv0.u = *(const uint4*)vr0;
    bv1.u = *(const uint4*)vr1;

    // ---- fixed-shift softmax + pack: p = exp2(s*C - M) ----
    float p00 = EXP2F(__builtin_fmaf(sa0[0], C_SCALE, -M_SHIFT));
    float p01 = EXP2F(__builtin_fmaf(sa0[1], C_SCALE, -M_SHIFT));
    float p02 = EXP2F(__builtin_fmaf(sa0[2], C_SCALE, -M_SHIFT));
    float p03 = EXP2F(__builtin_fmaf(sa0[3], C_SCALE, -M_SHIFT));
    float p10 = EXP2F(__builtin_fmaf(sa1[0], C_SCALE, -M_SHIFT));
    float p11 = EXP2F(__builtin_fmaf(sa1[1], C_SCALE, -M_SHIFT));
    float p12 = EXP2F(__builtin_fmaf(sa1[2], C_SCALE, -M_SHIFT));
    float p13 = EXP2F(__builtin_fmaf(sa1[3], C_SCALE, -M_SHIFT));
    la += ((p00 + p01) + (p02 + p03)) + ((p10 + p11) + (p12 + p13));
    unsigned w00 = cvtpk(p00, p01), w01 = cvtpk(p02, p03);
    unsigned w10 = cvtpk(p10, p11), w11 = cvtpk(p12, p13);

    // ---- P transpose in-register: pa = P[row=n][k = qd*8 .. +7] ----
    unsigned a0 = w00, b0 = w10; pls32(a0, b0); pls16(a0, b0);
    unsigned a1 = w01, b1 = w11; pls32(a1, b1); pls16(a1, b1);
    U4 pa; pa.u.x = a0; pa.u.y = a1; pa.u.z = b0; pa.u.w = b1;

    o0 = __builtin_amdgcn_mfma_f32_16x16x32_bf16(pa.v, bv0.v, o0, 0, 0, 0);
    o1 = __builtin_amdgcn_mfma_f32_16x16x32_bf16(pa.v, bv1.v, o1, 0, 0, 0);
  }

  // ---- conv weights (overlap the reduction below) ----
  float w9[2][9];
#pragma unroll
  for (int nt = 0; nt < 2; nt++){
    int c = head * 32 + nt * 16 + n;
#pragma unroll
    for (int t9 = 0; t9 < 9; t9++) w9[nt][t9] = cwg[c * 9 + t9];
  }

  // ---- cross-lane l reduction ----
  la += __shfl_xor(la, 16); la += __shfl_xor(la, 32);
  const float ila = 1.f / la;

  // ---- epilogue (single m-tile) ----
  {
    const int m0 = row0;
    float il[4];
#pragma unroll
    for (int r = 0; r < 4; r++) il[r] = __shfl(ila, qd * 4 + r);

    const int sp = (m0 >> 2) + qd;
    const int h_ = sp >> 1, w_ = sp & 1;

    float accs[2], cw2[2], vfs[2][4];
#pragma unroll
    for (int nt = 0; nt < 2; nt++){
      const int d = nt * 16 + n;
      const unsigned char* VTd = smem + VT_OFF + d * 1024;   // (d&7)==(n&7)
      float acc = 0.f;
#pragma unroll
      for (int dy = -1; dy <= 1; dy++){
        int h2 = h_ + dy;
        bool hv = (h2 >= 0) && (h2 <= 63);
        int h2c = hv ? h2 : h_;
#pragma unroll
        for (int wp = 0; wp < 2; wp++){
          bool valid = hv && !((dy == 0) && (wp == w_));
          int ti = (dy + 1) * 3 + 1 + wp - w_;
          int spn = h2c * 2 + wp;
          uint2 sv = *(const uint2*)(VTd + (((2 * spn) ^ swn) << 2));
          float s = bf2f((unsigned short)(sv.x & 0xffff)) + bf2f((unsigned short)(sv.x >> 16))
                  + bf2f((unsigned short)(sv.y & 0xffff)) + bf2f((unsigned short)(sv.y >> 16));
          acc += (valid ? w9[nt][ti] : 0.f) * s;
        }
      }
      accs[nt] = acc;
      cw2[nt] = w9[nt][4];
      uint2 vv4 = *(const uint2*)(VTd + ((((m0 >> 1) + 2 * qd) ^ swn) << 2));
      vfs[nt][0] = bf2f((unsigned short)(vv4.x & 0xffff));
      vfs[nt][1] = bf2f((unsigned short)(vv4.x >> 16));
      vfs[nt][2] = bf2f((unsigned short)(vv4.y & 0xffff));
      vfs[nt][3] = bf2f((unsigned short)(vv4.y >> 16));
    }

    const size_t obase = (size_t)b * 2097152 + (size_t)h_ * 32768 +
                         (size_t)(jj * 2 + w_) * 512 + head * 32;
#pragma unroll
    for (int r = 0; r < 4; r++){
      float r0 = o0[r] * il[r] + accs[0] + cw2[0] * vfs[0][r];
      float r1 = o1[r] * il[r] + accs[1] + cw2[1] * vfs[1][r];
      outg[obase + (size_t)r * 128 + n]      = r0;
      outg[obase + (size_t)r * 128 + 16 + n] = r1;
    }
  }
}

extern "C" void kernel_launch(void* const* d_in, const int* in_sizes, int n_in,
                              void* d_out, int out_size, void* d_ws, size_t ws_size,
                              hipStream_t stream) {
  (void)in_sizes; (void)n_in; (void)d_ws; (void)ws_size; (void)out_size;
  cswin_attn_kernel<<<dim3(1024), dim3(512), 0, stream>>>(
      (const float*)d_in[0], (const float*)d_in[1], (const float*)d_in[2],
      (const float*)d_in[3], (float*)d_out);
}

// Round 8
// 117.910 us; speedup vs baseline: 1.4150x; 1.4150x over previous
//
#include <hip/hip_runtime.h>
#include <stdint.h>

// CSWin attention, MI355X/gfx950 — r17: LDS-shared K + coalesced staging.
// Shapes: B=2, H=W=64, N=4, DIM=128, HEADS=4, HEAD_DIM=32, SPLIT=2.
// Grid 1024 = (window,head) x 4 row-quarters; block 256 (4 waves);
// wave = 32 q-rows (2 m-tiles). LDS 64KB: VT 32K + KS 32K -> 2 blocks/CU.
//
// r17 theory: clean rounds r9/r11/r12/r15 all ~60us with all pipes <=25%
// busy, invariant to VALU (r12: halved, no change), ILP (r15), TLP; spilled
// kernels (r13/r14) sustain 3.3 TB/s because spill is coalesced. The kernel
// is TRANSACTION-bound: K fragment gathers split 32 lines/instr and every
// wave re-gathers the whole K head-slice (2048 line-reqs/wave x 16 waves
// per win-head ~ 33k for data whose floor is 1k); V-stage splits 64/instr.
// ~51k line-reqs/CU ~ L2 request-rate limit ~ 60us. Changes:
//  * K staged ONCE per block to LDS (bf16 [tok][32ch], XOR-swizzled); hot
//    loop reads ak via ds_read_b128 — zero global loads in the loop.
//  * Coalesced stage pattern (8 lanes cover one token's 128B slice) for
//    K and V: 16 lines/instr. V written byte-granular (ds_write_b16) into
//    the unchanged VT layout (swizzle identical to read side).
//  * LDS 64KB -> 2 blocks/CU; launch_bounds(256,2) (r15-proven, ~104 VGPR).
// Predicted: dur 20-32us; VGPR ~100-128; WRITE 17-26MB (no spill);
// conflicts may rise to 1.5-3M (4-way ak reads, accepted). If dur ~60us
// clean -> transaction theory falsified -> hard floor, ROOFLINE.

typedef __bf16 bf16x8 __attribute__((ext_vector_type(8)));
typedef float f32x4 __attribute__((ext_vector_type(4)));
typedef float f32x2 __attribute__((ext_vector_type(2)));

#if __has_builtin(__builtin_amdgcn_exp2f)
#define EXP2F __builtin_amdgcn_exp2f
#else
#define EXP2F exp2f
#endif

union U4 { uint4 u; bf16x8 v; unsigned short s[8]; };

__device__ __forceinline__ float bf2f(unsigned short h){ union{unsigned u;float f;}x; x.u=((unsigned)h)<<16; return x.f; }

// f32 pair -> packed bf16 dword (lo in low half), RTNE. 1 instr.
__device__ __forceinline__ unsigned cvtpk(float lo, float hi){
  unsigned d;
  asm("v_cvt_pk_bf16_f32 %0, %1, %2" : "=v"(d) : "v"(lo), "v"(hi));
  return d;
}
__device__ __forceinline__ U4 pack8(float4 a, float4 b){
  U4 r;
  r.u.x = cvtpk(a.x, a.y); r.u.y = cvtpk(a.z, a.w);
  r.u.z = cvtpk(b.x, b.y); r.u.w = cvtpk(b.z, b.w);
  return r;
}

// permlane swap pair primitives (gfx950).
__device__ __forceinline__ void pls32(unsigned &a, unsigned &b){
#if __has_builtin(__builtin_amdgcn_permlane32_swap)
  auto r = __builtin_amdgcn_permlane32_swap(a, b, false, false);
  a = r[0]; b = r[1];
#else
  unsigned sa_ = __shfl_xor(a, 32), sb_ = __shfl_xor(b, 32);
  bool hi = ((threadIdx.x & 32) != 0);
  unsigned na = hi ? sb_ : a, nb = hi ? b : sa_;
  a = na; b = nb;
#endif
}
__device__ __forceinline__ void pls16(unsigned &a, unsigned &b){
#if __has_builtin(__builtin_amdgcn_permlane16_swap)
  auto r = __builtin_amdgcn_permlane16_swap(a, b, false, false);
  a = r[0]; b = r[1];
#else
  unsigned sa_ = __shfl_xor(a, 16), sb_ = __shfl_xor(b, 16);
  bool hi = ((threadIdx.x & 16) != 0);
  unsigned na = hi ? sb_ : a, nb = hi ? b : sa_;
  a = na; b = nb;
#endif
}

// In-register P transpose. Input: w[t][i] = packed P[q=n][k=16t+4*qd+{2i,2i+1}]
// Output A-frags: ap0 = P[row=n][k=qd*8..+7], ap1 = same for k+32.
__device__ __forceinline__ void xpose_p(const unsigned w[4][2], U4& ap0, U4& ap1)
{
  unsigned a0 = w[0][0], b0 = w[1][0]; pls32(a0, b0); pls16(a0, b0);
  unsigned a1 = w[0][1], b1 = w[1][1]; pls32(a1, b1); pls16(a1, b1);
  ap0.u.x = a0; ap0.u.y = a1; ap0.u.z = b0; ap0.u.w = b1;
  unsigned c0 = w[2][0], d0 = w[3][0]; pls32(c0, d0); pls16(c0, d0);
  unsigned c1 = w[2][1], d1 = w[3][1]; pls32(c1, d1); pls16(c1, d1);
  ap1.u.x = c0; ap1.u.y = c1; ap1.u.z = d0; ap1.u.w = d1;
}

#define C_SCALE 0.25506953149031837f  // (1/sqrt(32)) * log2(e)
#define M_SHIFT 20.0f                 // fixed log2-domain softmax shift

// LDS: VT bf16 [32 ch][512 tok], 1KB/row, byte = R*1024 + ((T*2)^((R&7)<<4))
//      KS bf16 [512 tok][32 ch], 64B/row, byte = T*64 + (off ^ ((T&3)<<4))
#define VT_OFF 0
#define KS_OFF 32768
#define LDS_BYTES 65536

__global__ __launch_bounds__(256, 2) void cswin_attn_kernel(
    const float* __restrict__ qg,
    const float* __restrict__ kg,
    const float* __restrict__ vg,
    const float* __restrict__ cwg,
    float* __restrict__ outg)
{
  __shared__ __align__(16) unsigned char smem[LDS_BYTES];
  const int tid = threadIdx.x;
  const int lane = tid & 63;
  const int wave = tid >> 6;
  const int qd = lane >> 4;
  const int n  = lane & 15;

  const int swn = (n & 7) << 2;            // VT read swizzle (dword units)
  const int xb0 = ((4 * qd) ^ swn) << 2;   // VT: byte off of swizzled dword 4qd
  const int xb1 = xb0 ^ 64;

  // XCD-sibling remap: q4-siblings share bid%8 (same XCD L2).
  const int bid = blockIdx.x;
  const int bh = ((bid >> 5) << 3) | (bid & 7);   // (window,head) 0..255
  const int q4 = (bid >> 3) & 3;                  // row-quarter 0..3
  const int head = bh & 3;
  const int bw = bh >> 2;
  const int b  = bw >> 5;
  const int jj = bw & 31;

  // token l: offset = wbase + (l>>3)*32768 + ((l>>2)&1)*512 + (l&3)*128
  const size_t wbase = (size_t)b * 2097152 + (size_t)(jj * 2) * 512 + head * 32;
  const size_t lane_base = wbase + (size_t)(n >> 3) * 32768 + (size_t)((n >> 2) & 1) * 512 +
                           (size_t)(n & 3) * 128 + qd * 8;

  const int row0  = q4 * 128 + wave * 32;
  const int tilea = row0 >> 4;          // even; m-tile B = tilea+1
  const int cka   = tilea >> 2;         // chunk holding both diag tiles
  const int ta    = tilea & 3;          // in-chunk tile idx of A's diag

  // ---- issue Q loads first (latency hidden under staging) ----
  float4 qra0, qra1, qrb0, qrb1;
  {
    const float* qa = qg + lane_base + (size_t)tilea * 65536;
    const float* qb = qa + 65536;
    qra0 = ((const float4*)qa)[0]; qra1 = ((const float4*)qa)[1];
    qrb0 = ((const float4*)qb)[0]; qrb1 = ((const float4*)qb)[1];
  }

  // ---- stage V -> VT and K -> KS, coalesced (8 lanes per token slice) ----
  // thread: token subgroup tk = tid>>3 (32 tokens/round), piece p = tid&7.
  {
    const int tk = tid >> 3;
    const int p  = tid & 7;
#pragma unroll 1
    for (int rr = 0; rr < 2; rr++){
      float4 va[8], ka[8];
#pragma unroll
      for (int r = 0; r < 8; r++){
        int T = (rr * 8 + r) * 32 + tk;
        size_t toff = wbase + (size_t)(T >> 3) * 32768 + (size_t)((T >> 2) & 1) * 512 +
                      (size_t)(T & 3) * 128 + p * 4;
        va[r] = *(const float4*)(vg + toff);
        ka[r] = *(const float4*)(kg + toff);
      }
#pragma unroll
      for (int r = 0; r < 8; r++){
        int T = (rr * 8 + r) * 32 + tk;
        // V: 4 bf16 byte-writes, rows R=4p+c, byte col T*2 (swizzled)
        unsigned short h0 = (unsigned short)cvtpk(va[r].x, va[r].x);
        unsigned short h1 = (unsigned short)cvtpk(va[r].y, va[r].y);
        unsigned short h2 = (unsigned short)cvtpk(va[r].z, va[r].z);
        unsigned short h3 = (unsigned short)cvtpk(va[r].w, va[r].w);
        int R0 = 4 * p;
        *(unsigned short*)(smem + VT_OFF + (R0+0) * 1024 + ((T*2) ^ (((R0+0)&7)<<4))) = h0;
        *(unsigned short*)(smem + VT_OFF + (R0+1) * 1024 + ((T*2) ^ (((R0+1)&7)<<4))) = h1;
        *(unsigned short*)(smem + VT_OFF + (R0+2) * 1024 + ((T*2) ^ (((R0+2)&7)<<4))) = h2;
        *(unsigned short*)(smem + VT_OFF + (R0+3) * 1024 + ((T*2) ^ (((R0+3)&7)<<4))) = h3;
        // K: one 8B write, row T, bytes p*8 (ch 4p..4p+3), swizzled
        uint2 kw; kw.x = cvtpk(ka[r].x, ka[r].y); kw.y = cvtpk(ka[r].z, ka[r].w);
        *(uint2*)(smem + KS_OFF + T * 64 + ((p*8) ^ ((T&3)<<4))) = kw;
      }
    }
  }

  __syncthreads();

  U4 bqa = pack8(qra0, qra1);
  U4 bqb = pack8(qrb0, qrb1);

  f32x4 o0a={0,0,0,0}, o1a={0,0,0,0}, o0b={0,0,0,0}, o1b={0,0,0,0};
  f32x2 la2 = {0.f,0.f}, lb2 = {0.f,0.f};   // packed per-lane softmax sums

  // per-lane KS read base: token n of each tile, ch qd*8..+7 (swizzled)
  const int kxb = (qd * 16) ^ ((n & 3) << 4);
  const unsigned char* kbase = smem + KS_OFF + n * 64 + kxb;

#pragma unroll 1
  for (int ck = 0; ck < 8; ck++){
    // ---- ak fragments from LDS (already bf16) ----
    U4 ak[4];
    const unsigned char* kb = kbase + ck * 4096;
    ak[0].u = *(const uint4*)(kb);
    ak[1].u = *(const uint4*)(kb + 1024);
    ak[2].u = *(const uint4*)(kb + 2048);
    ak[3].u = *(const uint4*)(kb + 3072);

    const f32x4 zero = {0.f,0.f,0.f,0.f};
    f32x4 sa[4], sb[4];
#pragma unroll
    for (int t = 0; t < 4; t++){
      sa[t] = __builtin_amdgcn_mfma_f32_16x16x32_bf16(ak[t].v, bqa.v, zero, 0, 0, 0);
      sb[t] = __builtin_amdgcn_mfma_f32_16x16x32_bf16(ak[t].v, bqb.v, zero, 0, 0, 0);
    }
    if (ck == cka){
      bool dq = (qd == (n >> 2));
#pragma unroll
      for (int r = 0; r < 4; r++)
        if (dq && r != (n & 3)){ sa[ta][r] = -1e30f; sb[ta+1][r] = -1e30f; }
    }

    // ---- fused softmax + pack (p = exp2(s*C - M)) ----
    unsigned wA[4][2], wB[4][2];
    {
      const f32x2 m2 = {-M_SHIFT, -M_SHIFT};
#pragma unroll
      for (int t = 0; t < 4; t++){
        f32x2 y0 = (f32x2){sa[t][0], sa[t][1]} * C_SCALE + m2;
        f32x2 y1 = (f32x2){sa[t][2], sa[t][3]} * C_SCALE + m2;
        float p0 = EXP2F(y0.x), p1 = EXP2F(y0.y);
        float p2 = EXP2F(y1.x), p3 = EXP2F(y1.y);
        la2 += (f32x2){p0, p1}; la2 += (f32x2){p2, p3};
        wA[t][0] = cvtpk(p0, p1); wA[t][1] = cvtpk(p2, p3);
      }
#pragma unroll
      for (int t = 0; t < 4; t++){
        f32x2 y0 = (f32x2){sb[t][0], sb[t][1]} * C_SCALE + m2;
        f32x2 y1 = (f32x2){sb[t][2], sb[t][3]} * C_SCALE + m2;
        float p0 = EXP2F(y0.x), p1 = EXP2F(y0.y);
        float p2 = EXP2F(y1.x), p3 = EXP2F(y1.y);
        lb2 += (f32x2){p0, p1}; lb2 += (f32x2){p2, p3};
        wB[t][0] = cvtpk(p0, p1); wB[t][1] = cvtpk(p2, p3);
      }
    }

    // ---- V fragments shared by both m-tiles (swizzled VT reads) ----
    const unsigned char* vr0 = smem + VT_OFF + n * 1024 + ck * 128;
    const unsigned char* vr1 = vr0 + 16 * 1024;
    U4 bv00, bv01, bv10, bv11;
    bv00.u = *(const uint4*)(vr0 + xb0);
    bv01.u = *(const uint4*)(vr0 + xb1);
    bv10.u = *(const uint4*)(vr1 + xb0);
    bv11.u = *(const uint4*)(vr1 + xb1);

    // ---- P transpose fully in-register (permlane swaps) ----
    U4 apA0, apA1, apB0, apB1;
    xpose_p(wA, apA0, apA1);
    xpose_p(wB, apB0, apB1);

    o0a = __builtin_amdgcn_mfma_f32_16x16x32_bf16(apA0.v, bv00.v, o0a, 0, 0, 0);
    o0a = __builtin_amdgcn_mfma_f32_16x16x32_bf16(apA1.v, bv01.v, o0a, 0, 0, 0);
    o1a = __builtin_amdgcn_mfma_f32_16x16x32_bf16(apA0.v, bv10.v, o1a, 0, 0, 0);
    o1a = __builtin_amdgcn_mfma_f32_16x16x32_bf16(apA1.v, bv11.v, o1a, 0, 0, 0);
    o0b = __builtin_amdgcn_mfma_f32_16x16x32_bf16(apB0.v, bv00.v, o0b, 0, 0, 0);
    o0b = __builtin_amdgcn_mfma_f32_16x16x32_bf16(apB1.v, bv01.v, o0b, 0, 0, 0);
    o1b = __builtin_amdgcn_mfma_f32_16x16x32_bf16(apB0.v, bv10.v, o1b, 0, 0, 0);
    o1b = __builtin_amdgcn_mfma_f32_16x16x32_bf16(apB1.v, bv11.v, o1b, 0, 0, 0);
  }

  // ---- conv weights (global loads overlap the reductions below) ----
  float w9[2][9];
#pragma unroll
  for (int nt = 0; nt < 2; nt++){
    int c = head * 32 + nt * 16 + n;
#pragma unroll
    for (int t9 = 0; t9 < 9; t9++) w9[nt][t9] = cwg[c * 9 + t9];
  }

  // ---- final cross-lane l reduction (once, not per chunk) ----
  float la = la2.x + la2.y, lb = lb2.x + lb2.y;
  la += __shfl_xor(la, 16); la += __shfl_xor(la, 32);
  lb += __shfl_xor(lb, 16); lb += __shfl_xor(lb, 32);

  const float ila = 1.f / la, ilb = 1.f / lb;

  // ---- epilogue: compute both nt halves first, then store adjacently ----
#pragma unroll
  for (int mt = 0; mt < 2; mt++){
    const int m0 = row0 + mt * 16;
    const float ilv = mt ? ilb : ila;
    const f32x4 oo0 = mt ? o0b : o0a;
    const f32x4 oo1 = mt ? o1b : o1a;
    float il[4];
#pragma unroll
    for (int r = 0; r < 4; r++) il[r] = __shfl(ilv, qd * 4 + r);

    const int sp = (m0 >> 2) + qd;
    const int h_ = sp >> 1, w_ = sp & 1;

    float accs[2], cw2[2], vfs[2][4];
#pragma unroll
    for (int nt = 0; nt < 2; nt++){
      const int d = nt * 16 + n;
      const unsigned char* VTd = smem + VT_OFF + d * 1024;   // (d&7)==(n&7)
      float acc = 0.f;
#pragma unroll
      for (int dy = -1; dy <= 1; dy++){
        int h2 = h_ + dy;
        bool hv = (h2 >= 0) && (h2 <= 63);
        int h2c = hv ? h2 : h_;   // safe in-range address for masked lanes
#pragma unroll
        for (int wp = 0; wp < 2; wp++){
          bool valid = hv && !((dy == 0) && (wp == w_));
          int ti = (dy + 1) * 3 + 1 + wp - w_;
          int spn = h2c * 2 + wp;
          uint2 sv = *(const uint2*)(VTd + (((2 * spn) ^ swn) << 2));
          float s = bf2f((unsigned short)(sv.x & 0xffff)) + bf2f((unsigned short)(sv.x >> 16))
                  + bf2f((unsigned short)(sv.y & 0xffff)) + bf2f((unsigned short)(sv.y >> 16));
          acc += (valid ? w9[nt][ti] : 0.f) * s;
        }
      }
      accs[nt] = acc;
      cw2[nt] = w9[nt][4];
      uint2 vv4 = *(const uint2*)(VTd + ((((m0 >> 1) + 2 * qd) ^ swn) << 2));
      vfs[nt][0] = bf2f((unsigned short)(vv4.x & 0xffff));
      vfs[nt][1] = bf2f((unsigned short)(vv4.x >> 16));
      vfs[nt][2] = bf2f((unsigned short)(vv4.y & 0xffff));
      vfs[nt][3] = bf2f((unsigned short)(vv4.y >> 16));
    }

    const size_t obase = (size_t)b * 2097152 + (size_t)h_ * 32768 +
                         (size_t)(jj * 2 + w_) * 512 + head * 32;
#pragma unroll
    for (int r = 0; r < 4; r++){
      float r0 = oo0[r] * il[r] + accs[0] + cw2[0] * vfs[0][r];
      float r1 = oo1[r] * il[r] + accs[1] + cw2[1] * vfs[1][r];
      outg[obase + (size_t)r * 128 + n]      = r0;   // line half 1
      outg[obase + (size_t)r * 128 + 16 + n] = r1;   // line half 2 (adjacent)
    }
  }
}

extern "C" void kernel_launch(void* const* d_in, const int* in_sizes, int n_in,
                              void* d_out, int out_size, void* d_ws, size_t ws_size,
                              hipStream_t stream) {
  (void)in_sizes; (void)n_in; (void)d_ws; (void)ws_size; (void)out_size;
  cswin_attn_kernel<<<dim3(1024), dim3(256), 0, stream>>>(
      (const float*)d_in[0], (const float*)d_in[1], (const float*)d_in[2],
      (const float*)d_in[3], (float*)d_out);
}

// Round 9
// 115.798 us; speedup vs baseline: 1.4408x; 1.0182x over previous
//
#include <hip/hip_runtime.h>
#include <stdint.h>

// CSWin attention, MI355X/gfx950 — r18: r17 memory structure + 2x TLP.
// Shapes: B=2, H=W=64, N=4, DIM=128, HEADS=4, HEAD_DIM=32, SPLIT=2.
// Grid 1024 = (window,head) x 4 row-quarters; block 512 (8 waves);
// wave = 16 q-rows (ONE m-tile). LDS 64KB: VT 32K + KS 32K -> 2 blocks/CU,
// 16 waves/CU = 4/SIMD (2x r17).
//
// r18 theory: r17's K-in-LDS confirmed the transaction bound (60->47us,
// WRITE=output exactly). Remaining: VALUBusy 48% at only 2 waves/SIMD
// (64KB LDS -> 2 blocks/CU of 4 waves) -> issue ports idle for lack of
// co-resident waves; V staging byte-writes are ~8-way bank conflicts
// (col depends only on tk: 8 values/wave -> 2.1M new conflict cycles).
// Changes:
//  * 512-thread blocks, 1 m-tile/wave: same LDS, 2x waves/SIMD.
//    launch_bounds(512,2) -> empirical cap 256/2=128 VGPR (r16's squeeze
//    was arg=8 -> cap 32; r10-14's was arg=4 -> cap 64).
//  * staging lanes re-mapped: tk=lane&31, ph=lane>>5; wave -> (token-half,
//    piece-pair). V-writes spread over all 32 banks at ~2-way (free);
//    K-writes ~2x4cy; global line counts unchanged.
//  * hot loop/epilogue: exact r17 math per m-tile, one tile per wave.
// Predicted: Occupancy 17->30-38, conflicts 2.85M->1.2-1.8M, VGPR 96-128
// with WRITE ~16.4MB clean, dur 47->33-38us. If dur ~47 unchanged at 2x
// occupancy -> per-CU serial resource (staging drain) is the floor ->
// overlap staging with first chunks next.

typedef __bf16 bf16x8 __attribute__((ext_vector_type(8)));
typedef float f32x4 __attribute__((ext_vector_type(4)));
typedef float f32x2 __attribute__((ext_vector_type(2)));

#if __has_builtin(__builtin_amdgcn_exp2f)
#define EXP2F __builtin_amdgcn_exp2f
#else
#define EXP2F exp2f
#endif

union U4 { uint4 u; bf16x8 v; unsigned short s[8]; };

__device__ __forceinline__ float bf2f(unsigned short h){ union{unsigned u;float f;}x; x.u=((unsigned)h)<<16; return x.f; }

// f32 pair -> packed bf16 dword (lo in low half), RTNE. 1 instr.
__device__ __forceinline__ unsigned cvtpk(float lo, float hi){
  unsigned d;
  asm("v_cvt_pk_bf16_f32 %0, %1, %2" : "=v"(d) : "v"(lo), "v"(hi));
  return d;
}
__device__ __forceinline__ U4 pack8(float4 a, float4 b){
  U4 r;
  r.u.x = cvtpk(a.x, a.y); r.u.y = cvtpk(a.z, a.w);
  r.u.z = cvtpk(b.x, b.y); r.u.w = cvtpk(b.z, b.w);
  return r;
}

// permlane swap pair primitives (gfx950).
__device__ __forceinline__ void pls32(unsigned &a, unsigned &b){
#if __has_builtin(__builtin_amdgcn_permlane32_swap)
  auto r = __builtin_amdgcn_permlane32_swap(a, b, false, false);
  a = r[0]; b = r[1];
#else
  unsigned sa_ = __shfl_xor(a, 32), sb_ = __shfl_xor(b, 32);
  bool hi = ((threadIdx.x & 32) != 0);
  unsigned na = hi ? sb_ : a, nb = hi ? b : sa_;
  a = na; b = nb;
#endif
}
__device__ __forceinline__ void pls16(unsigned &a, unsigned &b){
#if __has_builtin(__builtin_amdgcn_permlane16_swap)
  auto r = __builtin_amdgcn_permlane16_swap(a, b, false, false);
  a = r[0]; b = r[1];
#else
  unsigned sa_ = __shfl_xor(a, 16), sb_ = __shfl_xor(b, 16);
  bool hi = ((threadIdx.x & 16) != 0);
  unsigned na = hi ? sb_ : a, nb = hi ? b : sa_;
  a = na; b = nb;
#endif
}

// In-register P transpose. Input: w[t][i] = packed P[q=n][k=16t+4*qd+{2i,2i+1}]
// Output A-frags: ap0 = P[row=n][k=qd*8..+7], ap1 = same for k+32.
__device__ __forceinline__ void xpose_p(const unsigned w[4][2], U4& ap0, U4& ap1)
{
  unsigned a0 = w[0][0], b0 = w[1][0]; pls32(a0, b0); pls16(a0, b0);
  unsigned a1 = w[0][1], b1 = w[1][1]; pls32(a1, b1); pls16(a1, b1);
  ap0.u.x = a0; ap0.u.y = a1; ap0.u.z = b0; ap0.u.w = b1;
  unsigned c0 = w[2][0], d0 = w[3][0]; pls32(c0, d0); pls16(c0, d0);
  unsigned c1 = w[2][1], d1 = w[3][1]; pls32(c1, d1); pls16(c1, d1);
  ap1.u.x = c0; ap1.u.y = c1; ap1.u.z = d0; ap1.u.w = d1;
}

#define C_SCALE 0.25506953149031837f  // (1/sqrt(32)) * log2(e)
#define M_SHIFT 20.0f                 // fixed log2-domain softmax shift

// LDS: VT bf16 [32 ch][512 tok], 1KB/row, byte = R*1024 + ((T*2)^((R&7)<<4))
//      KS bf16 [512 tok][32 ch], 64B/row, byte = T*64 + (off ^ ((T&3)<<4))
#define VT_OFF 0
#define KS_OFF 32768
#define LDS_BYTES 65536

__global__ __launch_bounds__(512, 2) void cswin_attn_kernel(
    const float* __restrict__ qg,
    const float* __restrict__ kg,
    const float* __restrict__ vg,
    const float* __restrict__ cwg,
    float* __restrict__ outg)
{
  __shared__ __align__(16) unsigned char smem[LDS_BYTES];
  const int tid = threadIdx.x;
  const int lane = tid & 63;
  const int wave = tid >> 6;          // 0..7
  const int qd = lane >> 4;
  const int n  = lane & 15;

  const int swn = (n & 7) << 2;            // VT read swizzle (dword units)
  const int xb0 = ((4 * qd) ^ swn) << 2;   // VT: byte off of swizzled dword 4qd
  const int xb1 = xb0 ^ 64;

  // XCD-sibling remap: q4-siblings share bid%8 (same XCD L2).
  const int bid = blockIdx.x;
  const int bh = ((bid >> 5) << 3) | (bid & 7);   // (window,head) 0..255
  const int q4 = (bid >> 3) & 3;                  // row-quarter 0..3
  const int head = bh & 3;
  const int bw = bh >> 2;
  const int b  = bw >> 5;
  const int jj = bw & 31;

  // token l: offset = wbase + (l>>3)*32768 + ((l>>2)&1)*512 + (l&3)*128
  const size_t wbase = (size_t)b * 2097152 + (size_t)(jj * 2) * 512 + head * 32;
  const size_t lane_base = wbase + (size_t)(n >> 3) * 32768 + (size_t)((n >> 2) & 1) * 512 +
                           (size_t)(n & 3) * 128 + qd * 8;

  const int row0  = q4 * 128 + wave * 16;   // this wave's single m-tile
  const int tilea = row0 >> 4;              // 0..31
  const int cka   = tilea >> 2;             // chunk holding the diag tile
  const int ta    = tilea & 3;              // in-chunk slot (wave-uniform)

  // ---- issue Q loads first (latency hidden under staging) ----
  float4 qr0, qr1;
  {
    const float* qa = qg + lane_base + (size_t)tilea * 65536;
    qr0 = ((const float4*)qa)[0]; qr1 = ((const float4*)qa)[1];
  }

  // ---- stage V -> VT and K -> KS, coalesced, conflict-aware mapping ----
  // lane -> token tk (32/wave) x piece-half ph; wave -> token-half x piece-pair.
  {
    const int tk   = lane & 31;
    const int ph   = lane >> 5;
    const int half = wave >> 2;
    const int p    = 2 * (wave & 3) + ph;   // piece 0..7 (chs 4p..4p+3)
    const int Tb   = half * 256 + tk;
#pragma unroll 1
    for (int rr = 0; rr < 2; rr++){
      float4 va[4], ka[4];
#pragma unroll
      for (int r = 0; r < 4; r++){
        int T = Tb + (rr * 4 + r) * 32;
        size_t toff = wbase + (size_t)(T >> 3) * 32768 + (size_t)((T >> 2) & 1) * 512 +
                      (size_t)(T & 3) * 128 + p * 4;
        va[r] = *(const float4*)(vg + toff);
        ka[r] = *(const float4*)(kg + toff);
      }
#pragma unroll
      for (int r = 0; r < 4; r++){
        int T = Tb + (rr * 4 + r) * 32;
        // V: 4 bf16 byte-writes, rows R = 4p+c, byte col T*2 (swizzled)
        unsigned short h0 = (unsigned short)cvtpk(va[r].x, va[r].x);
        unsigned short h1 = (unsigned short)cvtpk(va[r].y, va[r].y);
        unsigned short h2 = (unsigned short)cvtpk(va[r].z, va[r].z);
        unsigned short h3 = (unsigned short)cvtpk(va[r].w, va[r].w);
        int R0 = 4 * p;
        *(unsigned short*)(smem + VT_OFF + (R0+0) * 1024 + ((T*2) ^ (((R0+0)&7)<<4))) = h0;
        *(unsigned short*)(smem + VT_OFF + (R0+1) * 1024 + ((T*2) ^ (((R0+1)&7)<<4))) = h1;
        *(unsigned short*)(smem + VT_OFF + (R0+2) * 1024 + ((T*2) ^ (((R0+2)&7)<<4))) = h2;
        *(unsigned short*)(smem + VT_OFF + (R0+3) * 1024 + ((T*2) ^ (((R0+3)&7)<<4))) = h3;
        // K: one 8B write, row T, bytes p*8 (ch 4p..4p+3), swizzled
        uint2 kw; kw.x = cvtpk(ka[r].x, ka[r].y); kw.y = cvtpk(ka[r].z, ka[r].w);
        *(uint2*)(smem + KS_OFF + T * 64 + ((p*8) ^ ((T&3)<<4))) = kw;
      }
    }
  }

  __syncthreads();

  U4 bq = pack8(qr0, qr1);

  f32x4 o0={0,0,0,0}, o1={0,0,0,0};
  f32x2 l2 = {0.f,0.f};                 // packed per-lane softmax sums

  // per-lane KS read base: token n of each tile, ch qd*8..+7 (swizzled)
  const int kxb = (qd * 16) ^ ((n & 3) << 4);
  const unsigned char* kbase = smem + KS_OFF + n * 64 + kxb;

#pragma unroll 1
  for (int ck = 0; ck < 8; ck++){
    // ---- ak fragments from LDS (already bf16) ----
    const unsigned char* kb = kbase + ck * 4096;
    U4 ak0, ak1, ak2, ak3;
    ak0.u = *(const uint4*)(kb);
    ak1.u = *(const uint4*)(kb + 1024);
    ak2.u = *(const uint4*)(kb + 2048);
    ak3.u = *(const uint4*)(kb + 3072);

    const f32x4 zero = {0.f,0.f,0.f,0.f};
    f32x4 sa0 = __builtin_amdgcn_mfma_f32_16x16x32_bf16(ak0.v, bq.v, zero, 0, 0, 0);
    f32x4 sa1 = __builtin_amdgcn_mfma_f32_16x16x32_bf16(ak1.v, bq.v, zero, 0, 0, 0);
    f32x4 sa2 = __builtin_amdgcn_mfma_f32_16x16x32_bf16(ak2.v, bq.v, zero, 0, 0, 0);
    f32x4 sa3 = __builtin_amdgcn_mfma_f32_16x16x32_bf16(ak3.v, bq.v, zero, 0, 0, 0);

    if (ck == cka){                      // diagonal chunk (wave-uniform)
      bool dq = (qd == (n >> 2));
#pragma unroll
      for (int r = 0; r < 4; r++){
        if (dq && r != (n & 3)){
          if (ta == 0)      sa0[r] = -1e30f;
          else if (ta == 1) sa1[r] = -1e30f;
          else if (ta == 2) sa2[r] = -1e30f;
          else              sa3[r] = -1e30f;
        }
      }
    }

    // ---- fused softmax + pack (p = exp2(s*C - M)) ----
    unsigned wv[4][2];
    {
      const f32x2 m2 = {-M_SHIFT, -M_SHIFT};
      f32x2 y0, y1; float p0, p1, p2, p3;
      y0 = (f32x2){sa0[0], sa0[1]} * C_SCALE + m2;
      y1 = (f32x2){sa0[2], sa0[3]} * C_SCALE + m2;
      p0 = EXP2F(y0.x); p1 = EXP2F(y0.y); p2 = EXP2F(y1.x); p3 = EXP2F(y1.y);
      l2 += (f32x2){p0, p1}; l2 += (f32x2){p2, p3};
      wv[0][0] = cvtpk(p0, p1); wv[0][1] = cvtpk(p2, p3);
      y0 = (f32x2){sa1[0], sa1[1]} * C_SCALE + m2;
      y1 = (f32x2){sa1[2], sa1[3]} * C_SCALE + m2;
      p0 = EXP2F(y0.x); p1 = EXP2F(y0.y); p2 = EXP2F(y1.x); p3 = EXP2F(y1.y);
      l2 += (f32x2){p0, p1}; l2 += (f32x2){p2, p3};
      wv[1][0] = cvtpk(p0, p1); wv[1][1] = cvtpk(p2, p3);
      y0 = (f32x2){sa2[0], sa2[1]} * C_SCALE + m2;
      y1 = (f32x2){sa2[2], sa2[3]} * C_SCALE + m2;
      p0 = EXP2F(y0.x); p1 = EXP2F(y0.y); p2 = EXP2F(y1.x); p3 = EXP2F(y1.y);
      l2 += (f32x2){p0, p1}; l2 += (f32x2){p2, p3};
      wv[2][0] = cvtpk(p0, p1); wv[2][1] = cvtpk(p2, p3);
      y0 = (f32x2){sa3[0], sa3[1]} * C_SCALE + m2;
      y1 = (f32x2){sa3[2], sa3[3]} * C_SCALE + m2;
      p0 = EXP2F(y0.x); p1 = EXP2F(y0.y); p2 = EXP2F(y1.x); p3 = EXP2F(y1.y);
      l2 += (f32x2){p0, p1}; l2 += (f32x2){p2, p3};
      wv[3][0] = cvtpk(p0, p1); wv[3][1] = cvtpk(p2, p3);
    }

    // ---- V fragments (swizzled VT reads) ----
    const unsigned char* vr0 = smem + VT_OFF + n * 1024 + ck * 128;
    const unsigned char* vr1 = vr0 + 16 * 1024;
    U4 bv00, bv01, bv10, bv11;
    bv00.u = *(const uint4*)(vr0 + xb0);
    bv01.u = *(const uint4*)(vr0 + xb1);
    bv10.u = *(const uint4*)(vr1 + xb0);
    bv11.u = *(const uint4*)(vr1 + xb1);

    // ---- P transpose fully in-register (permlane swaps) ----
    U4 ap0, ap1;
    xpose_p(wv, ap0, ap1);

    o0 = __builtin_amdgcn_mfma_f32_16x16x32_bf16(ap0.v, bv00.v, o0, 0, 0, 0);
    o0 = __builtin_amdgcn_mfma_f32_16x16x32_bf16(ap1.v, bv01.v, o0, 0, 0, 0);
    o1 = __builtin_amdgcn_mfma_f32_16x16x32_bf16(ap0.v, bv10.v, o1, 0, 0, 0);
    o1 = __builtin_amdgcn_mfma_f32_16x16x32_bf16(ap1.v, bv11.v, o1, 0, 0, 0);
  }

  // ---- conv weights (global loads overlap the reduction below) ----
  float w9[2][9];
#pragma unroll
  for (int nt = 0; nt < 2; nt++){
    int c = head * 32 + nt * 16 + n;
#pragma unroll
    for (int t9 = 0; t9 < 9; t9++) w9[nt][t9] = cwg[c * 9 + t9];
  }

  // ---- cross-lane l reduction ----
  float la = l2.x + l2.y;
  la += __shfl_xor(la, 16); la += __shfl_xor(la, 32);
  const float ila = 1.f / la;

  // ---- epilogue (single m-tile) ----
  {
    const int m0 = row0;
    float il[4];
#pragma unroll
    for (int r = 0; r < 4; r++) il[r] = __shfl(ila, qd * 4 + r);

    const int sp = (m0 >> 2) + qd;
    const int h_ = sp >> 1, w_ = sp & 1;

    float accs[2], cw2[2], vfs[2][4];
#pragma unroll
    for (int nt = 0; nt < 2; nt++){
      const int d = nt * 16 + n;
      const unsigned char* VTd = smem + VT_OFF + d * 1024;   // (d&7)==(n&7)
      float acc = 0.f;
#pragma unroll
      for (int dy = -1; dy <= 1; dy++){
        int h2 = h_ + dy;
        bool hv = (h2 >= 0) && (h2 <= 63);
        int h2c = hv ? h2 : h_;   // safe in-range address for masked lanes
#pragma unroll
        for (int wp = 0; wp < 2; wp++){
          bool valid = hv && !((dy == 0) && (wp == w_));
          int ti = (dy + 1) * 3 + 1 + wp - w_;
          int spn = h2c * 2 + wp;
          uint2 sv = *(const uint2*)(VTd + (((2 * spn) ^ swn) << 2));
          float s = bf2f((unsigned short)(sv.x & 0xffff)) + bf2f((unsigned short)(sv.x >> 16))
                  + bf2f((unsigned short)(sv.y & 0xffff)) + bf2f((unsigned short)(sv.y >> 16));
          acc += (valid ? w9[nt][ti] : 0.f) * s;
        }
      }
      accs[nt] = acc;
      cw2[nt] = w9[nt][4];
      uint2 vv4 = *(const uint2*)(VTd + ((((m0 >> 1) + 2 * qd) ^ swn) << 2));
      vfs[nt][0] = bf2f((unsigned short)(vv4.x & 0xffff));
      vfs[nt][1] = bf2f((unsigned short)(vv4.x >> 16));
      vfs[nt][2] = bf2f((unsigned short)(vv4.y & 0xffff));
      vfs[nt][3] = bf2f((unsigned short)(vv4.y >> 16));
    }

    const size_t obase = (size_t)b * 2097152 + (size_t)h_ * 32768 +
                         (size_t)(jj * 2 + w_) * 512 + head * 32;
#pragma unroll
    for (int r = 0; r < 4; r++){
      float r0 = o0[r] * il[r] + accs[0] + cw2[0] * vfs[0][r];
      float r1 = o1[r] * il[r] + accs[1] + cw2[1] * vfs[1][r];
      outg[obase + (size_t)r * 128 + n]      = r0;   // line half 1
      outg[obase + (size_t)r * 128 + 16 + n] = r1;   // line half 2 (adjacent)
    }
  }
}

extern "C" void kernel_launch(void* const* d_in, const int* in_sizes, int n_in,
                              void* d_out, int out_size, void* d_ws, size_t ws_size,
                              hipStream_t stream) {
  (void)in_sizes; (void)n_in; (void)d_ws; (void)ws_size; (void)out_size;
  cswin_attn_kernel<<<dim3(1024), dim3(512), 0, stream>>>(
      (const float*)d_in[0], (const float*)d_in[1], (const float*)d_in[2],
      (const float*)d_in[3], (float*)d_out);
}

// Round 10
// 112.881 us; speedup vs baseline: 1.4781x; 1.0258x over previous
//
#include <hip/hip_runtime.h>
#include <stdint.h>

// CSWin attention, MI355X/gfx950 — r19: stage once per win-head (grid 256).
// Shapes: B=2, H=W=64, N=4, DIM=128, HEADS=4, HEAD_DIM=32, SPLIT=2.
// Grid 256 = (window,head), 1 block/CU exactly; block 1024 (16 waves);
// wave = 32 q-rows (2 m-tiles, r17's proven hot loop). LDS 64KB: VT+KS.
//
// r19 post-mortem of r18: TLP x2 gave only 5%; two derivation errors found:
//  (a) r18 staging mapped 32 DIFFERENT tokens per instr (tk=lane&31) ->
//      ~32-64 lines/instr, reintroducing the transaction problem r17 fixed;
//  (b) KS swizzle key (T&3) doesn't separate hot rows n,n+4,n+8,n+12 ->
//      ak reads were 4-way bank conflicts all along.
//  (c) the 4 q4-siblings each stage the SAME K/V -> 4x redundant staging,
//      grid ran as 2 resident rounds.
// Changes:
//  * grid 256 x block 1024: one block per win-head, staging /4, no rounds;
//    16 waves/CU = 4/SIMD retained; each wave = r17's 2-m-tile loop.
//  * staging: T = rr*128 + (tid>>3), p = tid&7 (8 lanes per token's 128B,
//    2 lines/instr); all 8 loads issued before writes.
//  * KS swizzle key ((T>>1)&3)<<4 (write) / ((n>>1)&3)<<4 (read): ak reads
//    become 2-way (free).
//  * launch_bounds(1024,1): VGPR cap 256 (empirical cap=256/arg), no squeeze.
// Predicted: dur 28-35us, conflicts 3.1M->0.5-0.8M, VGPR 88-110,
// WRITE ~16.4MB. If dur >=42us clean -> staging wasn't the cost; suspect
// effective clock / per-CU serial floor -> honest roofline assessment next.

typedef __bf16 bf16x8 __attribute__((ext_vector_type(8)));
typedef float f32x4 __attribute__((ext_vector_type(4)));
typedef float f32x2 __attribute__((ext_vector_type(2)));

#if __has_builtin(__builtin_amdgcn_exp2f)
#define EXP2F __builtin_amdgcn_exp2f
#else
#define EXP2F exp2f
#endif

union U4 { uint4 u; bf16x8 v; unsigned short s[8]; };

__device__ __forceinline__ float bf2f(unsigned short h){ union{unsigned u;float f;}x; x.u=((unsigned)h)<<16; return x.f; }

// f32 pair -> packed bf16 dword (lo in low half), RTNE. 1 instr.
__device__ __forceinline__ unsigned cvtpk(float lo, float hi){
  unsigned d;
  asm("v_cvt_pk_bf16_f32 %0, %1, %2" : "=v"(d) : "v"(lo), "v"(hi));
  return d;
}
__device__ __forceinline__ U4 pack8(float4 a, float4 b){
  U4 r;
  r.u.x = cvtpk(a.x, a.y); r.u.y = cvtpk(a.z, a.w);
  r.u.z = cvtpk(b.x, b.y); r.u.w = cvtpk(b.z, b.w);
  return r;
}

// permlane swap pair primitives (gfx950).
__device__ __forceinline__ void pls32(unsigned &a, unsigned &b){
#if __has_builtin(__builtin_amdgcn_permlane32_swap)
  auto r = __builtin_amdgcn_permlane32_swap(a, b, false, false);
  a = r[0]; b = r[1];
#else
  unsigned sa_ = __shfl_xor(a, 32), sb_ = __shfl_xor(b, 32);
  bool hi = ((threadIdx.x & 32) != 0);
  unsigned na = hi ? sb_ : a, nb = hi ? b : sa_;
  a = na; b = nb;
#endif
}
__device__ __forceinline__ void pls16(unsigned &a, unsigned &b){
#if __has_builtin(__builtin_amdgcn_permlane16_swap)
  auto r = __builtin_amdgcn_permlane16_swap(a, b, false, false);
  a = r[0]; b = r[1];
#else
  unsigned sa_ = __shfl_xor(a, 16), sb_ = __shfl_xor(b, 16);
  bool hi = ((threadIdx.x & 16) != 0);
  unsigned na = hi ? sb_ : a, nb = hi ? b : sa_;
  a = na; b = nb;
#endif
}

// In-register P transpose. Input: w[t][i] = packed P[q=n][k=16t+4*qd+{2i,2i+1}]
// Output A-frags: ap0 = P[row=n][k=qd*8..+7], ap1 = same for k+32.
__device__ __forceinline__ void xpose_p(const unsigned w[4][2], U4& ap0, U4& ap1)
{
  unsigned a0 = w[0][0], b0 = w[1][0]; pls32(a0, b0); pls16(a0, b0);
  unsigned a1 = w[0][1], b1 = w[1][1]; pls32(a1, b1); pls16(a1, b1);
  ap0.u.x = a0; ap0.u.y = a1; ap0.u.z = b0; ap0.u.w = b1;
  unsigned c0 = w[2][0], d0 = w[3][0]; pls32(c0, d0); pls16(c0, d0);
  unsigned c1 = w[2][1], d1 = w[3][1]; pls32(c1, d1); pls16(c1, d1);
  ap1.u.x = c0; ap1.u.y = c1; ap1.u.z = d0; ap1.u.w = d1;
}

#define C_SCALE 0.25506953149031837f  // (1/sqrt(32)) * log2(e)
#define M_SHIFT 20.0f                 // fixed log2-domain softmax shift

// LDS: VT bf16 [32 ch][512 tok], 1KB/row, byte = R*1024 + ((T*2)^((R&7)<<4))
//      KS bf16 [512 tok][32 ch], 64B/row, byte = T*64 + (off ^ (((T>>1)&3)<<4))
#define VT_OFF 0
#define KS_OFF 32768
#define LDS_BYTES 65536

__global__ __launch_bounds__(1024, 1) void cswin_attn_kernel(
    const float* __restrict__ qg,
    const float* __restrict__ kg,
    const float* __restrict__ vg,
    const float* __restrict__ cwg,
    float* __restrict__ outg)
{
  __shared__ __align__(16) unsigned char smem[LDS_BYTES];
  const int tid = threadIdx.x;
  const int lane = tid & 63;
  const int wave = tid >> 6;          // 0..15
  const int qd = lane >> 4;
  const int n  = lane & 15;

  const int swn = (n & 7) << 2;            // VT read swizzle (dword units)
  const int xb0 = ((4 * qd) ^ swn) << 2;   // VT: byte off of swizzled dword 4qd
  const int xb1 = xb0 ^ 64;

  const int bh = blockIdx.x;               // (window,head) 0..255
  const int head = bh & 3;
  const int bw = bh >> 2;
  const int b  = bw >> 5;
  const int jj = bw & 31;

  // token l: offset = wbase + (l>>3)*32768 + ((l>>2)&1)*512 + (l&3)*128
  const size_t wbase = (size_t)b * 2097152 + (size_t)(jj * 2) * 512 + head * 32;
  const size_t lane_base = wbase + (size_t)(n >> 3) * 32768 + (size_t)((n >> 2) & 1) * 512 +
                           (size_t)(n & 3) * 128 + qd * 8;

  const int row0  = wave * 32;          // this wave's 2 m-tiles
  const int tilea = row0 >> 4;          // even; m-tile B = tilea+1
  const int cka   = tilea >> 2;         // chunk holding both diag tiles
  const int ta    = tilea & 3;          // in-chunk tile idx of A's diag

  // ---- issue Q loads first (latency hidden under staging) ----
  float4 qra0, qra1, qrb0, qrb1;
  {
    const float* qa = qg + lane_base + (size_t)tilea * 65536;
    const float* qb = qa + 65536;
    qra0 = ((const float4*)qa)[0]; qra1 = ((const float4*)qa)[1];
    qrb0 = ((const float4*)qb)[0]; qrb1 = ((const float4*)qb)[1];
  }

  // ---- stage V -> VT and K -> KS, once per win-head, coalesced ----
  // slice (T, p): T = rr*128 + tid>>3, p = tid&7 (8 lanes = one token's 128B).
  {
    const int tk = tid >> 3;
    const int p  = tid & 7;
    float4 va0, va1, va2, va3, ka0, ka1, ka2, ka3;
    {
      size_t o0 = wbase + (size_t)((tk) >> 3) * 32768 + (size_t)(((tk) >> 2) & 1) * 512 + (size_t)((tk) & 3) * 128 + p * 4;
      size_t o1 = wbase + (size_t)((128 + tk) >> 3) * 32768 + (size_t)(((128 + tk) >> 2) & 1) * 512 + (size_t)((128 + tk) & 3) * 128 + p * 4;
      size_t o2 = wbase + (size_t)((256 + tk) >> 3) * 32768 + (size_t)(((256 + tk) >> 2) & 1) * 512 + (size_t)((256 + tk) & 3) * 128 + p * 4;
      size_t o3 = wbase + (size_t)((384 + tk) >> 3) * 32768 + (size_t)(((384 + tk) >> 2) & 1) * 512 + (size_t)((384 + tk) & 3) * 128 + p * 4;
      va0 = *(const float4*)(vg + o0); ka0 = *(const float4*)(kg + o0);
      va1 = *(const float4*)(vg + o1); ka1 = *(const float4*)(kg + o1);
      va2 = *(const float4*)(vg + o2); ka2 = *(const float4*)(kg + o2);
      va3 = *(const float4*)(vg + o3); ka3 = *(const float4*)(kg + o3);
    }
    const int R0 = 4 * p;
#define STAGE_WR(VA, KA, TT)                                                         \
    {                                                                                \
      const int T_ = (TT);                                                           \
      unsigned short h0 = (unsigned short)cvtpk((VA).x, (VA).x);                     \
      unsigned short h1 = (unsigned short)cvtpk((VA).y, (VA).y);                     \
      unsigned short h2 = (unsigned short)cvtpk((VA).z, (VA).z);                     \
      unsigned short h3 = (unsigned short)cvtpk((VA).w, (VA).w);                     \
      *(unsigned short*)(smem + VT_OFF + (R0+0) * 1024 + ((T_*2) ^ (((R0+0)&7)<<4))) = h0; \
      *(unsigned short*)(smem + VT_OFF + (R0+1) * 1024 + ((T_*2) ^ (((R0+1)&7)<<4))) = h1; \
      *(unsigned short*)(smem + VT_OFF + (R0+2) * 1024 + ((T_*2) ^ (((R0+2)&7)<<4))) = h2; \
      *(unsigned short*)(smem + VT_OFF + (R0+3) * 1024 + ((T_*2) ^ (((R0+3)&7)<<4))) = h3; \
      uint2 kw; kw.x = cvtpk((KA).x, (KA).y); kw.y = cvtpk((KA).z, (KA).w);          \
      *(uint2*)(smem + KS_OFF + T_ * 64 + ((p*8) ^ (((T_>>1)&3)<<4))) = kw;          \
    }
    STAGE_WR(va0, ka0, tk)
    STAGE_WR(va1, ka1, 128 + tk)
    STAGE_WR(va2, ka2, 256 + tk)
    STAGE_WR(va3, ka3, 384 + tk)
#undef STAGE_WR
  }

  __syncthreads();

  U4 bqa = pack8(qra0, qra1);
  U4 bqb = pack8(qrb0, qrb1);

  f32x4 o0a={0,0,0,0}, o1a={0,0,0,0}, o0b={0,0,0,0}, o1b={0,0,0,0};
  f32x2 la2 = {0.f,0.f}, lb2 = {0.f,0.f};   // packed per-lane softmax sums

  // per-lane KS read base: token n of each tile, ch qd*8..+7 (swizzled).
  // swizzle key for row T=16t+n is ((T>>1)&3) = ((n>>1)&3)  (16t ≡ 0 mod 8).
  const int kxb = (qd * 16) ^ (((n >> 1) & 3) << 4);
  const unsigned char* kbase = smem + KS_OFF + n * 64 + kxb;

#pragma unroll 1
  for (int ck = 0; ck < 8; ck++){
    // ---- ak fragments from LDS (already bf16), 2-way banks (free) ----
    U4 ak[4];
    const unsigned char* kb = kbase + ck * 4096;
    ak[0].u = *(const uint4*)(kb);
    ak[1].u = *(const uint4*)(kb + 1024);
    ak[2].u = *(const uint4*)(kb + 2048);
    ak[3].u = *(const uint4*)(kb + 3072);

    const f32x4 zero = {0.f,0.f,0.f,0.f};
    f32x4 sa[4], sb[4];
#pragma unroll
    for (int t = 0; t < 4; t++){
      sa[t] = __builtin_amdgcn_mfma_f32_16x16x32_bf16(ak[t].v, bqa.v, zero, 0, 0, 0);
      sb[t] = __builtin_amdgcn_mfma_f32_16x16x32_bf16(ak[t].v, bqb.v, zero, 0, 0, 0);
    }
    if (ck == cka){
      bool dq = (qd == (n >> 2));
#pragma unroll
      for (int r = 0; r < 4; r++)
        if (dq && r != (n & 3)){ sa[ta][r] = -1e30f; sb[ta+1][r] = -1e30f; }
    }

    // ---- fused softmax + pack (p = exp2(s*C - M)) ----
    unsigned wA[4][2], wB[4][2];
    {
      const f32x2 m2 = {-M_SHIFT, -M_SHIFT};
#pragma unroll
      for (int t = 0; t < 4; t++){
        f32x2 y0 = (f32x2){sa[t][0], sa[t][1]} * C_SCALE + m2;
        f32x2 y1 = (f32x2){sa[t][2], sa[t][3]} * C_SCALE + m2;
        float p0 = EXP2F(y0.x), p1 = EXP2F(y0.y);
        float p2 = EXP2F(y1.x), p3 = EXP2F(y1.y);
        la2 += (f32x2){p0, p1}; la2 += (f32x2){p2, p3};
        wA[t][0] = cvtpk(p0, p1); wA[t][1] = cvtpk(p2, p3);
      }
#pragma unroll
      for (int t = 0; t < 4; t++){
        f32x2 y0 = (f32x2){sb[t][0], sb[t][1]} * C_SCALE + m2;
        f32x2 y1 = (f32x2){sb[t][2], sb[t][3]} * C_SCALE + m2;
        float p0 = EXP2F(y0.x), p1 = EXP2F(y0.y);
        float p2 = EXP2F(y1.x), p3 = EXP2F(y1.y);
        lb2 += (f32x2){p0, p1}; lb2 += (f32x2){p2, p3};
        wB[t][0] = cvtpk(p0, p1); wB[t][1] = cvtpk(p2, p3);
      }
    }

    // ---- V fragments shared by both m-tiles (swizzled VT reads) ----
    const unsigned char* vr0 = smem + VT_OFF + n * 1024 + ck * 128;
    const unsigned char* vr1 = vr0 + 16 * 1024;
    U4 bv00, bv01, bv10, bv11;
    bv00.u = *(const uint4*)(vr0 + xb0);
    bv01.u = *(const uint4*)(vr0 + xb1);
    bv10.u = *(const uint4*)(vr1 + xb0);
    bv11.u = *(const uint4*)(vr1 + xb1);

    // ---- P transpose fully in-register (permlane swaps) ----
    U4 apA0, apA1, apB0, apB1;
    xpose_p(wA, apA0, apA1);
    xpose_p(wB, apB0, apB1);

    o0a = __builtin_amdgcn_mfma_f32_16x16x32_bf16(apA0.v, bv00.v, o0a, 0, 0, 0);
    o0a = __builtin_amdgcn_mfma_f32_16x16x32_bf16(apA1.v, bv01.v, o0a, 0, 0, 0);
    o1a = __builtin_amdgcn_mfma_f32_16x16x32_bf16(apA0.v, bv10.v, o1a, 0, 0, 0);
    o1a = __builtin_amdgcn_mfma_f32_16x16x32_bf16(apA1.v, bv11.v, o1a, 0, 0, 0);
    o0b = __builtin_amdgcn_mfma_f32_16x16x32_bf16(apB0.v, bv00.v, o0b, 0, 0, 0);
    o0b = __builtin_amdgcn_mfma_f32_16x16x32_bf16(apB1.v, bv01.v, o0b, 0, 0, 0);
    o1b = __builtin_amdgcn_mfma_f32_16x16x32_bf16(apB0.v, bv10.v, o1b, 0, 0, 0);
    o1b = __builtin_amdgcn_mfma_f32_16x16x32_bf16(apB1.v, bv11.v, o1b, 0, 0, 0);
  }

  // ---- conv weights (global loads overlap the reductions below) ----
  float w9[2][9];
#pragma unroll
  for (int nt = 0; nt < 2; nt++){
    int c = head * 32 + nt * 16 + n;
#pragma unroll
    for (int t9 = 0; t9 < 9; t9++) w9[nt][t9] = cwg[c * 9 + t9];
  }

  // ---- final cross-lane l reduction (once, not per chunk) ----
  float la = la2.x + la2.y, lb = lb2.x + lb2.y;
  la += __shfl_xor(la, 16); la += __shfl_xor(la, 32);
  lb += __shfl_xor(lb, 16); lb += __shfl_xor(lb, 32);

  const float ila = 1.f / la, ilb = 1.f / lb;

  // ---- epilogue: compute both nt halves first, then store adjacently ----
#pragma unroll
  for (int mt = 0; mt < 2; mt++){
    const int m0 = row0 + mt * 16;
    const float ilv = mt ? ilb : ila;
    const f32x4 oo0 = mt ? o0b : o0a;
    const f32x4 oo1 = mt ? o1b : o1a;
    float il[4];
#pragma unroll
    for (int r = 0; r < 4; r++) il[r] = __shfl(ilv, qd * 4 + r);

    const int sp = (m0 >> 2) + qd;
    const int h_ = sp >> 1, w_ = sp & 1;

    float accs[2], cw2[2], vfs[2][4];
#pragma unroll
    for (int nt = 0; nt < 2; nt++){
      const int d = nt * 16 + n;
      const unsigned char* VTd = smem + VT_OFF + d * 1024;   // (d&7)==(n&7)
      float acc = 0.f;
#pragma unroll
      for (int dy = -1; dy <= 1; dy++){
        int h2 = h_ + dy;
        bool hv = (h2 >= 0) && (h2 <= 63);
        int h2c = hv ? h2 : h_;   // safe in-range address for masked lanes
#pragma unroll
        for (int wp = 0; wp < 2; wp++){
          bool valid = hv && !((dy == 0) && (wp == w_));
          int ti = (dy + 1) * 3 + 1 + wp - w_;
          int spn = h2c * 2 + wp;
          uint2 sv = *(const uint2*)(VTd + (((2 * spn) ^ swn) << 2));
          float s = bf2f((unsigned short)(sv.x & 0xffff)) + bf2f((unsigned short)(sv.x >> 16))
                  + bf2f((unsigned short)(sv.y & 0xffff)) + bf2f((unsigned short)(sv.y >> 16));
          acc += (valid ? w9[nt][ti] : 0.f) * s;
        }
      }
      accs[nt] = acc;
      cw2[nt] = w9[nt][4];
      uint2 vv4 = *(const uint2*)(VTd + ((((m0 >> 1) + 2 * qd) ^ swn) << 2));
      vfs[nt][0] = bf2f((unsigned short)(vv4.x & 0xffff));
      vfs[nt][1] = bf2f((unsigned short)(vv4.x >> 16));
      vfs[nt][2] = bf2f((unsigned short)(vv4.y & 0xffff));
      vfs[nt][3] = bf2f((unsigned short)(vv4.y >> 16));
    }

    const size_t obase = (size_t)b * 2097152 + (size_t)h_ * 32768 +
                         (size_t)(jj * 2 + w_) * 512 + head * 32;
#pragma unroll
    for (int r = 0; r < 4; r++){
      float r0 = oo0[r] * il[r] + accs[0] + cw2[0] * vfs[0][r];
      float r1 = oo1[r] * il[r] + accs[1] + cw2[1] * vfs[1][r];
      outg[obase + (size_t)r * 128 + n]      = r0;   // line half 1
      outg[obase + (size_t)r * 128 + 16 + n] = r1;   // line half 2 (adjacent)
    }
  }
}

extern "C" void kernel_launch(void* const* d_in, const int* in_sizes, int n_in,
                              void* d_out, int out_size, void* d_ws, size_t ws_size,
                              hipStream_t stream) {
  (void)in_sizes; (void)n_in; (void)d_ws; (void)ws_size; (void)out_size;
  cswin_attn_kernel<<<dim3(256), dim3(1024), 0, stream>>>(
      (const float*)d_in[0], (const float*)d_in[1], (const float*)d_in[2],
      (const float*)d_in[3], (float*)d_out);
}